// Round 6
// baseline (313.307 us; speedup 1.0000x reference)
//
#include <hip/hip_runtime.h>
#include <hip/hip_bf16.h>

#define NS 100          /* steps: s=2(k-1)+p, p=0 sin, p=1 cos */
#define TILE_BYTES 4096 /* B step-tile: [c=0..3][col=0..63] 16B chunks (8 kappa) */

typedef float f32x4 __attribute__((ext_vector_type(4)));
typedef float f32x2 __attribute__((ext_vector_type(2)));
typedef short s16x8 __attribute__((ext_vector_type(8)));
typedef unsigned int u32x4 __attribute__((ext_vector_type(4)));

static __device__ __forceinline__ unsigned int cvtpk(float a, float b) {
  unsigned int r;
  asm("v_cvt_pk_bf16_f32 %0, %1, %2" : "=v"(r) : "v"(a), "v"(b));
  return r;
}

// Bt tile (q = nt*16+sp, s): [c][col] 16B chunks: byte = c*1024 + col*16,
// chunk = 8 bf16 of C[f(s)][i = sp*32 + c*8 + j][nt*64 + col], j at byte 2j.
// Transpose done per-thread (8 strided scalar reads, coalesced across lanes).
// Blocks 0..1023 also zero `out`.
__global__ void fkan_prep(const float* __restrict__ C, unsigned short* __restrict__ Bt,
                          float* __restrict__ out) {
  const int bx = blockIdx.x;           // 0..12799 = q*100 + s
  const int s = bx % NS;
  const int q = bx / NS;               // stream 0..127
  const int sp = q & 15, nt = q >> 4;
  const int f = (s >> 1) + 50 * (s & 1);
  const int t = threadIdx.x;           // 256

  if (bx < 1024) {                     // zero out: 2048*512 f32 = 1024 * 4KB
    f32x4 z = {0.f, 0.f, 0.f, 0.f};
    *(f32x4*)(out + (size_t)bx * 1024 + t * 4) = z;
  }

  const int c = t >> 6, col = t & 63;
  const float* src = C + ((size_t)f * 512 + sp * 32 + c * 8) * 512 + nt * 64 + col;
  float v[8];
  #pragma unroll
  for (int j = 0; j < 8; ++j) v[j] = src[(size_t)j * 512];
  u32x4 p;
  p[0] = cvtpk(v[0], v[1]);
  p[1] = cvtpk(v[2], v[3]);
  p[2] = cvtpk(v[4], v[5]);
  p[3] = cvtpk(v[6], v[7]);
  *(u32x4*)((char*)Bt + (size_t)bx * TILE_BYTES + t * 16) = p;
}

__global__ __launch_bounds__(64, 2) void fkan_gemm(
    const float* __restrict__ x, const unsigned short* __restrict__ Bt,
    const float* __restrict__ bias, float* __restrict__ out) {
  // wave-private LDS: 4 buffers, depth-3 staging, NO barriers anywhere
  __shared__ __attribute__((aligned(16))) char Bs[4][TILE_BYTES];  // 16KB

  const int lane = threadIdx.x;        // 0..63 (one wave per block)
  const int d    = blockIdx.x;         // 0..4095
  const int xcd  = d & 7;
  const int u    = d >> 3;             // 0..511
  const int g    = xcd * 16 + (u >> 5);          // stream 0..127, fixed per XCD
  const int mt   = u & 31;
  const int nt   = g >> 4, sp = g & 15;
  const int m0 = mt * 64, n0 = nt * 64;
  const int lrow = lane & 15, lkg = lane >> 4;

  // ---- recurrence state: 32 x per lane (4 rows x 8 i), f32x2-packed ----
  f32x2 sk[4][4], ck[4][4], s1[4][4], c1[4][4];
  #pragma unroll
  for (int mi = 0; mi < 4; ++mi) {
    const float* xp = x + (size_t)(m0 + mi * 16 + lrow) * 512 + sp * 32 + lkg * 8;
    f32x4 xa = *(const f32x4*)xp;
    f32x4 xb = *(const f32x4*)(xp + 4);
    #pragma unroll
    for (int p = 0; p < 4; ++p) {
      #pragma unroll
      for (int e = 0; e < 2; ++e) {
        int j = p * 2 + e;
        float xv = (j < 4) ? xa[j] : xb[j - 4];
        float r = xv * 0.5f;                       // revs: sin(pi x)=sin(2pi(x/2))
        asm("v_fract_f32 %0, %1" : "=v"(r) : "v"(r));
        float sv, cv;
        asm("v_sin_f32 %0, %1" : "=v"(sv) : "v"(r));
        asm("v_cos_f32 %0, %1" : "=v"(cv) : "v"(r));
        s1[mi][p][e] = sv; c1[mi][p][e] = cv;
        sk[mi][p][e] = sv; ck[mi][p][e] = cv;      // k = 1
      }
    }
  }

  f32x4 acc[4][4];
  #pragma unroll
  for (int mi = 0; mi < 4; ++mi)
    #pragma unroll
    for (int ni = 0; ni < 4; ++ni)
      acc[mi][ni] = (f32x4){0.f, 0.f, 0.f, 0.f};

  const char* gp = (const char*)Bt + (size_t)(nt * 16 + sp) * NS * TILE_BYTES + lane * 16;

  auto stage = [&](int s) {            // 4 glds x 1KB; buffer s&3
    const char* p = gp + (size_t)s * TILE_BYTES;
    #pragma unroll
    for (int h = 0; h < 4; ++h)
      __builtin_amdgcn_global_load_lds(
          (const __attribute__((address_space(1))) unsigned int*)(p + h * 1024),
          (__attribute__((address_space(3))) unsigned int*)(&Bs[s & 3][h * 1024 + lane * 16]),
          16, 0, 0);
  };

  // wait_sel: 2 -> vmcnt(8), 1 -> vmcnt(4), 0 -> vmcnt(0)
  auto iter = [&](int s, f32x2 (&st)[4][4], int wait_sel, bool do_stage) {
    if (wait_sel == 2)      asm volatile("s_waitcnt vmcnt(8)" ::: "memory");
    else if (wait_sel == 1) asm volatile("s_waitcnt vmcnt(4)" ::: "memory");
    else                    asm volatile("s_waitcnt vmcnt(0)" ::: "memory");
    // stage buffer (s+3)&3 == (s-1)&3: read last iter, lgkm-retired -> safe
    if (do_stage) stage(s + 3);
    const char* base = &Bs[s & 3][0] + lkg * 1024 + lrow * 16;
    s16x8 bfr[4];
    #pragma unroll
    for (int ni = 0; ni < 4; ++ni)
      bfr[ni] = *(const s16x8*)(base + ni * 256);
    __builtin_amdgcn_s_setprio(1);
    #pragma unroll
    for (int mi = 0; mi < 4; ++mi) {
      u32x4 pk;
      pk[0] = cvtpk(st[mi][0][0], st[mi][0][1]);
      pk[1] = cvtpk(st[mi][1][0], st[mi][1][1]);
      pk[2] = cvtpk(st[mi][2][0], st[mi][2][1]);
      pk[3] = cvtpk(st[mi][3][0], st[mi][3][1]);
      s16x8 af = __builtin_bit_cast(s16x8, pk);
      #pragma unroll
      for (int ni = 0; ni < 4; ++ni)
        acc[mi][ni] = __builtin_amdgcn_mfma_f32_16x16x32_bf16(af, bfr[ni], acc[mi][ni], 0, 0, 0);
    }
    __builtin_amdgcn_s_setprio(0);
  };

  auto recur = [&]() {
    #pragma unroll
    for (int mi = 0; mi < 4; ++mi)
      #pragma unroll
      for (int p = 0; p < 4; ++p) {
        f32x2 so = sk[mi][p], co = ck[mi][p];
        sk[mi][p] = so * c1[mi][p] + co * s1[mi][p];
        ck[mi][p] = co * c1[mi][p] - so * s1[mi][p];
      }
  };

  stage(0); stage(1); stage(2);        // 12 loads outstanding
  #pragma unroll 1
  for (int kh = 0; kh < 49; ++kh) {
    iter(2 * kh,     sk, 2, true);               // stages tile 2kh+3
    iter(2 * kh + 1, ck, 2, (2 * kh + 1) <= 96); // kh=48: s=97, no stage
    recur();
  }
  iter(98, sk, 1, false);
  iter(99, ck, 0, false);

  // ---- epilogue: atomic accumulate; bias from split 0 only ----
  #pragma unroll
  for (int ni = 0; ni < 4; ++ni) {
    const int col = n0 + ni * 16 + lrow;
    const float bv = (sp == 0) ? bias[col] : 0.0f;
    #pragma unroll
    for (int mi = 0; mi < 4; ++mi) {
      const int row = m0 + mi * 16 + lkg * 4;
      #pragma unroll
      for (int j = 0; j < 4; ++j)
        atomicAdd(out + (size_t)(row + j) * 512 + col, acc[mi][ni][j] + bv);
    }
  }
}

extern "C" void kernel_launch(void* const* d_in, const int* in_sizes, int n_in,
                              void* d_out, int out_size, void* d_ws, size_t ws_size,
                              hipStream_t stream) {
  const float* x    = (const float*)d_in[0];
  const float* C    = (const float*)d_in[1];
  const float* bias = (const float*)d_in[2];
  float* out = (float*)d_out;
  unsigned short* Bt = (unsigned short*)d_ws;   // 128 streams * 100 * 4KB = 52.4 MB

  fkan_prep<<<dim3(12800), dim3(256), 0, stream>>>(C, Bt, out);
  fkan_gemm<<<dim3(4096), dim3(64), 0, stream>>>(x, Bt, bias, out);
}